// Round 8
// baseline (535.307 us; speedup 1.0000x reference)
//
#include <hip/hip_runtime.h>

typedef __bf16 bf16_t;
typedef __bf16 bf16x8 __attribute__((ext_vector_type(8)));
typedef float f32x4 __attribute__((ext_vector_type(4)));
typedef int   int4v __attribute__((ext_vector_type(4)));

#define LOG2E 1.4426950408889634f

template<int CTRL>
__device__ __forceinline__ float qperm(float x) {
  return __builtin_bit_cast(float,
      __builtin_amdgcn_update_dpp(0, __builtin_bit_cast(int, x), CTRL, 0xF, 0xF, true));
}
template<int CTRL>
__device__ __forceinline__ int qpermi(int x) {
  return __builtin_amdgcn_update_dpp(0, x, CTRL, 0xF, 0xF, true);
}

// LDS-only barrier: does NOT drain vmcnt, so global loads/stores stay in
// flight across steps (compiler's __syncthreads drains vmcnt(0) every step).
__device__ __forceinline__ void lds_barrier() {
  asm volatile("s_waitcnt lgkmcnt(0)\n\ts_barrier" ::: "memory");
}

// ---------------------------------------------------------------------------
// K1: preT[dir][r][t] = mult_p * ((Wih_dir @ x[t_x]) + bih + bhh),
//     gate-interleaved rows r = 4n + p <-> original row j = 125*p + n.
//     mult_p = -2*LOG2E for p==2 (tanh gate), else -LOG2E  — pre-folded so
//     the LSTM hot loop's exp2 argument is fma(gsel, dscale, pv) directly.
//     t_x = t (fwd) or 511-t (bwd).
// MFMA GEMM with bf16 hi/lo split (fp32-exact to ~2^-18).
// grid = 64 blocks (dir*32 + row-tile T), 256 threads (4 waves).
// ---------------------------------------------------------------------------
__global__ __launch_bounds__(256) void pre_kernel(
    const float* __restrict__ x,     // [512][125]
    const float* __restrict__ Wih_f, const float* __restrict__ bih_f,
    const float* __restrict__ bhh_f,
    const float* __restrict__ Wih_b, const float* __restrict__ bih_b,
    const float* __restrict__ bhh_b,
    float* __restrict__ preT)        // [2][512 r][512 t]
{
  const int dir = blockIdx.x >> 5;
  const int T   = blockIdx.x & 31;
  const float* __restrict__ Wih = dir ? Wih_b : Wih_f;
  const float* __restrict__ bih = dir ? bih_b : bih_f;
  const float* __restrict__ bhh = dir ? bhh_b : bhh_f;

  const int tid = threadIdx.x;
  const int wv  = tid >> 6;
  const int lane = tid & 63;
  const int q = lane >> 4, cc = lane & 15;

  // A fragments: row r = 16T + cc, k = 32ks + 8q + j
  const int r  = 16 * T + cc;
  const int na = r >> 2, pa = r & 3;
  const bool vld = (na < 125);
  const float* __restrict__ Wr = Wih + (vld ? (125 * pa + na) * 125 : 0);

  bf16x8 whi[4], wlo[4];
  #pragma unroll
  for (int ks = 0; ks < 4; ++ks) {
    #pragma unroll
    for (int j = 0; j < 8; ++j) {
      int k = 32 * ks + 8 * q + j;
      float wvv = (vld && k < 125) ? Wr[k] : 0.0f;
      bf16_t hi = (bf16_t)wvv;
      whi[ks][j] = hi;
      wlo[ks][j] = (bf16_t)(wvv - (float)hi);
    }
  }

  // rows this lane stores: ro = 16T + 4q + reg  ->  gate p == reg (mod-4 = 0)
  float bias[4];
  #pragma unroll
  for (int reg = 0; reg < 4; ++reg) {
    int ro = 16 * T + 4 * q + reg;
    int no = ro >> 2, po = ro & 3;
    bias[reg] = (no < 125) ? (bih[125 * po + no] + bhh[125 * po + no]) : 0.0f;
  }

  for (int i = 0; i < 8; ++i) {
    const int tt = 8 * wv + i;
    const int t  = 16 * tt + cc;
    const int trow = dir ? (511 - t) : t;
    const float* __restrict__ xr = x + trow * 125;

    f32x4 acc = (f32x4)0.0f;
    #pragma unroll
    for (int ks = 0; ks < 4; ++ks) {
      bf16x8 xhi, xlo;
      #pragma unroll
      for (int j = 0; j < 8; ++j) {
        int k = 32 * ks + 8 * q + j;
        float xv = (k < 125) ? xr[k] : 0.0f;
        bf16_t hi = (bf16_t)xv;
        xhi[j] = hi;
        xlo[j] = (bf16_t)(xv - (float)hi);
      }
      acc = __builtin_amdgcn_mfma_f32_16x16x32_bf16(whi[ks], xhi, acc, 0, 0, 0);
      acc = __builtin_amdgcn_mfma_f32_16x16x32_bf16(whi[ks], xlo, acc, 0, 0, 0);
      acc = __builtin_amdgcn_mfma_f32_16x16x32_bf16(wlo[ks], xhi, acc, 0, 0, 0);
    }
    #pragma unroll
    for (int reg = 0; reg < 4; ++reg) {
      int ro = 16 * T + 4 * q + reg;
      const float multp = (reg == 2) ? (-2.0f * LOG2E) : (-LOG2E);
      preT[dir * 262144 + ro * 512 + 16 * tt + cc] = multp * (acc[reg] + bias[reg]);
    }
  }
}

// ---------------------------------------------------------------------------
// K2: sequential LSTM, sdot4 quad k-split, BOTH dirs in ONE block.
// grid = 1 block, 1024 threads (16 waves = 4 waves/SIMD on one CU).
// dir = tid>>9; within a dir: quad = unit n; lane 4n+p handles all 4 gate
// rows of unit n on k-quarter p (8 packed-i8 dwords per row).  4 independent
// wave-chains per SIMD interleave through every latency segment (ds_read,
// exp2->rcp, DPP) — round-7 lesson: 2 waves/SIMD left ~55% idle.
// Quarter partials reduced in-quad via DPP butterfly; lane p takes gate p.
// ---------------------------------------------------------------------------
__global__ __launch_bounds__(1024, 4) void lstm_kernel(
    const float* __restrict__ Whh_f, const float* __restrict__ Whh_b,
    const float* __restrict__ pre,   // [2][512 r][512 t]  (mult pre-folded)
    bf16_t* __restrict__ h_all)      // [512][256]  (0:125 fwd | 125:250 bwd | 250:256 zero)
{
  const int tid = threadIdx.x;
  const int dir = tid >> 9;
  const float* __restrict__ Whh = dir ? Whh_b : Whh_f;

  const int w   = tid >> 6;       // wave 0..15
  const int p   = tid & 3;        // k-quarter AND own gate index
  const int Q   = (tid >> 2) & 127;  // unit index [0,128)
  const bool valid = (Q < 125);

  // ---- pass 1: global max |Whh| over both dirs (shared scale) ----
  float wm = 0.0f;
  if (valid) {
    #pragma unroll
    for (int g = 0; g < 4; ++g) {
      const float* __restrict__ Wrow = Whh + (125 * g + Q) * 125;
      #pragma unroll
      for (int kk = 0; kk < 32; ++kk) {
        int k = 32 * p + kk;
        if (k < 125) wm = fmaxf(wm, fabsf(Wrow[k]));
      }
    }
  }
  #pragma unroll
  for (int off = 1; off < 64; off <<= 1)
    wm = fmaxf(wm, __shfl_xor(wm, off));
  __shared__ float wmx[16];
  if ((tid & 63) == 0) wmx[w] = wm;
  __syncthreads();
  float wmax = wmx[0];
  #pragma unroll
  for (int u = 1; u < 16; ++u) wmax = fmaxf(wmax, wmx[u]);
  const float s_w  = 127.0f / wmax;
  const float invq = wmax / (127.0f * 127.0f);   // int D -> W@h

  // ---- pass 2: quantize W: wq[gate][8 dwords], k = 32p + 4d + byte ----
  int wq[4][8];
  #pragma unroll
  for (int g = 0; g < 4; ++g) {
    const float* __restrict__ Wrow = Whh + (valid ? (125 * g + Q) * 125 : 0);
    #pragma unroll
    for (int d = 0; d < 8; ++d) {
      int b = 0;
      #pragma unroll
      for (int byte = 0; byte < 4; ++byte) {
        int k = 32 * p + 4 * d + byte;
        int qv = 0;
        if (valid && k < 125)
          qv = (int)__builtin_rintf(Wrow[k] * s_w);
        b |= (qv & 0xFF) << (8 * byte);
      }
      wq[g][d] = b;
    }
  }

  __shared__ __align__(16) char hbuf[2][2][128];   // [dir][buf][unit]
  if (tid < 512) ((char*)hbuf)[tid] = 0;
  // zero h_all pad columns once
  if (tid < 512) {
    #pragma unroll
    for (int u = 0; u < 6; ++u) h_all[tid * 256 + 250 + u] = (bf16_t)0.0f;
  }
  __syncthreads();

  const float mult   = (p == 2) ? (-2.0f * LOG2E) : (-LOG2E);
  const float sA     = (p == 2) ? 2.0f : 1.0f;
  const float sB     = (p == 2) ? -1.0f : 0.0f;
  const float dscale = mult * invq;              // int D -> exp2 argument
  const float* __restrict__ preR = pre + dir * 262144 + (tid & 511) * 512;
  float c = 0.0f;

  float4 pv_cur = *(const float4*)preR;

  for (int gg = 0; gg < 128; ++gg) {
    float4 pv_nxt = make_float4(0.f, 0.f, 0.f, 0.f);
    if (gg < 127) pv_nxt = *(const float4*)(preR + 4 * (gg + 1));

    #pragma unroll
    for (int s4 = 0; s4 < 4; ++s4) {
      const int step = 4 * gg + s4;
      const int cur  = s4 & 1, nxt = cur ^ 1;
      const float pv = (s4 == 0) ? pv_cur.x : (s4 == 1) ? pv_cur.y
                     : (s4 == 2) ? pv_cur.z : pv_cur.w;   // already mult-scaled

      // this lane's k-quarter of h: 32 B, two b128 reads (disjoint banks)
      const int4v hv0 = *(const int4v*)&hbuf[dir][cur][32 * p];
      const int4v hv1 = *(const int4v*)&hbuf[dir][cur][32 * p + 16];

      // per gate row: 8-deep sdot chain over the quarter (4 indep chains)
      int acc[4];
      #pragma unroll
      for (int g = 0; g < 4; ++g) {
        int a = 0;
        a = __builtin_amdgcn_sdot4(wq[g][0], hv0[0], a, false);
        a = __builtin_amdgcn_sdot4(wq[g][1], hv0[1], a, false);
        a = __builtin_amdgcn_sdot4(wq[g][2], hv0[2], a, false);
        a = __builtin_amdgcn_sdot4(wq[g][3], hv0[3], a, false);
        a = __builtin_amdgcn_sdot4(wq[g][4], hv1[0], a, false);
        a = __builtin_amdgcn_sdot4(wq[g][5], hv1[1], a, false);
        a = __builtin_amdgcn_sdot4(wq[g][6], hv1[2], a, false);
        a = __builtin_amdgcn_sdot4(wq[g][7], hv1[3], a, false);
        acc[g] = a;
      }

      // quad butterfly: sum the 4 quarters (all lanes get all 4 row sums)
      #pragma unroll
      for (int g = 0; g < 4; ++g) {
        int s1 = acc[g] + qpermi<0xB1>(acc[g]);   // xor1: quad_perm(1,0,3,2)
        acc[g] = s1 + qpermi<0x4E>(s1);           // xor2: quad_perm(2,3,0,1)
      }
      // lane p takes gate p
      int g01  = (p & 1) ? acc[1] : acc[0];
      int g23  = (p & 1) ? acc[3] : acc[2];
      int gsel = (p & 2) ? g23 : g01;

      // uniform activation: act = sA*sigmoid-form + sB   (pv pre-scaled)
      float xg  = fmaf((float)gsel, dscale, pv);
      float e   = __builtin_amdgcn_exp2f(xg);
      float y   = __builtin_amdgcn_rcpf(1.0f + e);
      float act = fmaf(y, sA, sB);

      // quad p0=i, p1=f, p2=g~, p3=o  (flat broadcasts)
      float b_i = qperm<0x00>(act);
      float b_f = qperm<0x55>(act);
      float b_g = qperm<0xAA>(act);
      float b_o = qperm<0xFF>(act);
      c = fmaf(b_f, c, b_i * b_g);               // c = f*c + i*g~
      float e2 = __builtin_amdgcn_exp2f(-2.0f * LOG2E * c);
      float tc = fmaf(__builtin_amdgcn_rcpf(1.0f + e2), 2.0f, -1.0f);
      float h  = b_o * tc;

      if (p == 0) {
        hbuf[dir][nxt][Q] = (char)(int)__builtin_rintf(h * 127.0f);
        if (Q < 125) {
          int t_orig = dir ? (511 - step) : step;
          h_all[t_orig * 256 + dir * 125 + Q] = (bf16_t)h;
        }
      }
      lds_barrier();
    }
    pv_cur = pv_nxt;
  }
}

// ---------------------------------------------------------------------------
// K3: Qa[j][m] = C2 * (h @ W1[:, :250].T),  Qb[j][m] = C2 * (h @ W1[:, 250:].T + b1)
//     C2 = 2*log2(e) folded in for K4's exp2.  bf16 MFMA, one 16x16 tile/wave.
//     Also zeroes `out` for K4's atomic accumulation (replaces the memset).
// ---------------------------------------------------------------------------
__global__ __launch_bounds__(256) void qgemm_kernel(
    const bf16_t* __restrict__ h_all, // [512][256]
    const float* __restrict__ W1,     // [512][500]
    const float* __restrict__ b1,     // [512]
    float* __restrict__ Qa,           // [512][512]
    float* __restrict__ Qb,           // [512][512]
    float* __restrict__ out)          // [512*512] zeroed here
{
  const int tid  = threadIdx.x;
  const int wv   = tid >> 6;
  const int lane = tid & 63;
  const int q    = lane >> 4, cc = lane & 15;
  const int bj   = blockIdx.x & 31;    // j tile
  const int bm   = blockIdx.x >> 5;    // m group
  const int m    = bm * 64 + wv * 16 + cc;   // [0,1024)
  const int j0   = bj * 16;
  const int jA   = j0 + cc;

  out[blockIdx.x * 512 + tid]       = 0.0f;
  out[blockIdx.x * 512 + tid + 256] = 0.0f;

  const bool isB = (m >= 512);
  const int  row = isB ? (m - 512) : m;
  const int  cof = isB ? 250 : 0;

  f32x4 acc = (f32x4)0.0f;
  #pragma unroll
  for (int ks = 0; ks < 8; ++ks) {
    int kb = 32 * ks + 8 * q;
    bf16x8 a = *(const bf16x8*)&h_all[jA * 256 + kb];
    bf16x8 b;
    #pragma unroll
    for (int jj = 0; jj < 8; ++jj) {
      int k = kb + jj;
      float v = (k < 250) ? W1[row * 500 + cof + k] : 0.0f;
      b[jj] = (bf16_t)v;
    }
    acc = __builtin_amdgcn_mfma_f32_16x16x32_bf16(a, b, acc, 0, 0, 0);
  }

  const float C2 = 2.0f * LOG2E;
  #pragma unroll
  for (int reg = 0; reg < 4; ++reg) {
    int j = j0 + 4 * q + reg;
    float v = acc[reg];
    if (!isB) Qa[j * 512 + m] = C2 * v;
    else      Qb[j * 512 + (m - 512)] = C2 * (v + b1[m - 512]);
  }
}

// ---------------------------------------------------------------------------
// K4: out[i][j] = b2 + sum_k W2[k] * tanh(...)
//     tanh = 1 - 2*rcp(1 + exp2(sa[j,k] + sb[i,k]))   (C2 pre-folded)
//     split-K x2 (512 blocks, 2/CU); partials via atomicAdd into zeroed out.
// ---------------------------------------------------------------------------
__global__ __launch_bounds__(256) void outer_kernel(
    const float* __restrict__ Qa, const float* __restrict__ Qb,
    const float* __restrict__ W2, const float* __restrict__ b2,
    float* __restrict__ out)
{
  __shared__ float sa[2][32][33];
  __shared__ float sb[2][32][33];
  __shared__ float sw[2][32];

  const int tid  = threadIdx.x;
  const int bk   = blockIdx.x >> 8;          // k half 0/1
  const int tile = blockIdx.x & 255;
  const int bi   = tile >> 4, bjx = tile & 15;
  const int i0   = bi * 32, j0 = bjx * 32;
  const int ii0  = (tid & 15) * 2;
  const int jj0  = (tid >> 4) * 2;
  const int ljj  = tid & 31, kk4 = (tid >> 5) * 4;
  const int kbase = bk * 256;

  float accR[2][2] = {{0.0f, 0.0f}, {0.0f, 0.0f}};
  float wsum = 0.0f;

  for (int kc = 0; kc < 8; ++kc) {
    const int buf = kc & 1;
    const int k0  = kbase + kc * 32;
    float4 va = *(const float4*)&Qa[(j0 + ljj) * 512 + k0 + kk4];
    float4 vb = *(const float4*)&Qb[(i0 + ljj) * 512 + k0 + kk4];
    sa[buf][kk4 + 0][ljj] = va.x; sa[buf][kk4 + 1][ljj] = va.y;
    sa[buf][kk4 + 2][ljj] = va.z; sa[buf][kk4 + 3][ljj] = va.w;
    sb[buf][kk4 + 0][ljj] = vb.x; sb[buf][kk4 + 1][ljj] = vb.y;
    sb[buf][kk4 + 2][ljj] = vb.z; sb[buf][kk4 + 3][ljj] = vb.w;
    if (tid < 32) sw[buf][tid] = W2[k0 + tid];
    __syncthreads();

    #pragma unroll 4
    for (int kk = 0; kk < 32; ++kk) {
      float2 av = *(const float2*)&sa[buf][kk][jj0];
      float2 bv = *(const float2*)&sb[buf][kk][ii0];
      float wk = sw[buf][kk];
      wsum += wk;
      {
        float e = __builtin_amdgcn_exp2f(av.x + bv.x);
        accR[0][0] = fmaf(wk, __builtin_amdgcn_rcpf(1.0f + e), accR[0][0]);
      }
      {
        float e = __builtin_amdgcn_exp2f(av.y + bv.x);
        accR[0][1] = fmaf(wk, __builtin_amdgcn_rcpf(1.0f + e), accR[0][1]);
      }
      {
        float e = __builtin_amdgcn_exp2f(av.x + bv.y);
        accR[1][0] = fmaf(wk, __builtin_amdgcn_rcpf(1.0f + e), accR[1][0]);
      }
      {
        float e = __builtin_amdgcn_exp2f(av.y + bv.y);
        accR[1][1] = fmaf(wk, __builtin_amdgcn_rcpf(1.0f + e), accR[1][1]);
      }
    }
  }

  const float bb = (bk == 0) ? b2[0] : 0.0f;
  #pragma unroll
  for (int i2 = 0; i2 < 2; ++i2)
    #pragma unroll
    for (int j2 = 0; j2 < 2; ++j2)
      atomicAdd(&out[(i0 + ii0 + i2) * 512 + (j0 + jj0 + j2)],
                wsum - 2.0f * accR[i2][j2] + bb);
}

// ---------------------------------------------------------------------------
extern "C" void kernel_launch(void* const* d_in, const int* in_sizes, int n_in,
                              void* d_out, int out_size, void* d_ws, size_t ws_size,
                              hipStream_t stream) {
  const float* emb   = (const float*)d_in[0];
  const float* Wih_f = (const float*)d_in[1];
  const float* Whh_f = (const float*)d_in[2];
  const float* bih_f = (const float*)d_in[3];
  const float* bhh_f = (const float*)d_in[4];
  const float* Wih_b = (const float*)d_in[5];
  const float* Whh_b = (const float*)d_in[6];
  const float* bih_b = (const float*)d_in[7];
  const float* bhh_b = (const float*)d_in[8];
  const float* W1    = (const float*)d_in[9];
  const float* b1    = (const float*)d_in[10];
  const float* W2    = (const float*)d_in[11];
  const float* b2    = (const float*)d_in[12];
  float* out = (float*)d_out;

  char* ws = (char*)d_ws;
  float*  pre   = (float*)ws;                                  // 2 MB
  bf16_t* h_all = (bf16_t*)(ws + 2 * 1024 * 1024);             // 256 KB
  float*  Qa    = (float*)(ws + 2 * 1024 * 1024 + 256 * 1024); // 1 MB
  float*  Qb    = Qa + 512 * 512;                              // 1 MB

  pre_kernel<<<64, 256, 0, stream>>>(emb, Wih_f, bih_f, bhh_f,
                                     Wih_b, bih_b, bhh_b, pre);
  lstm_kernel<<<1, 1024, 0, stream>>>(Whh_f, Whh_b, pre, h_all);
  qgemm_kernel<<<512, 256, 0, stream>>>(h_all, W1, b1, Qa, Qb, out);
  outer_kernel<<<512, 256, 0, stream>>>(Qa, Qb, W2, b2, out);
}